// Round 1
// 665.629 us; speedup vs baseline: 1.0203x; 1.0203x over previous
//
#include <hip/hip_runtime.h>
#include <hip/hip_bf16.h>
#include <stdint.h>

typedef unsigned short u16;
typedef __bf16 bf16x8 __attribute__((ext_vector_type(8)));
typedef unsigned short u16x8 __attribute__((ext_vector_type(8)));
typedef float f32x4 __attribute__((ext_vector_type(4)));

__device__ __forceinline__ float bf2f(u16 h) {
  union { uint32_t u; float f; } x;
  x.u = ((uint32_t)h) << 16;
  return x.f;
}
__device__ __forceinline__ u16 f2bf(float f) {
  union { float f; uint32_t u; } x;
  x.f = f;
  uint32_t r = x.u + 0x7FFFu + ((x.u >> 16) & 1u);  // round-to-nearest-even
  return (u16)(r >> 16);
}

// async global->LDS, 16B per lane. LDS dest must be wave-uniform base + lane*16.
__device__ __forceinline__ void gload_lds16(const u16* g, u16* l) {
  __builtin_amdgcn_global_load_lds(
      (const __attribute__((address_space(1))) uint32_t*)g,
      (__attribute__((address_space(3))) uint32_t*)l, 16, 0, 0);
}

// One fused fp32->bf16 convert for x, W_qkv, W_o. Counts are 8-elem chunks.
__global__ __launch_bounds__(256) void cvt_all(
    const float* __restrict__ x, const float* __restrict__ w1,
    const float* __restrict__ w2, u16* __restrict__ xb,
    u16* __restrict__ w1b, u16* __restrict__ w2b, int n1, int n2, int n3) {
  int i = blockIdx.x * 256 + threadIdx.x;
  const float* src;
  u16* dst;
  int j = i;
  if (i < n1) { src = x; dst = xb; }
  else if (i < n1 + n2) { src = w1; dst = w1b; j = i - n1; }
  else if (i < n1 + n2 + n3) { src = w2; dst = w2b; j = i - n1 - n2; }
  else return;
  const float4* p = (const float4*)src + (size_t)j * 2;
  float4 a = p[0], b = p[1];
  u16x8 o;
  o[0] = f2bf(a.x); o[1] = f2bf(a.y); o[2] = f2bf(a.z); o[3] = f2bf(a.w);
  o[4] = f2bf(b.x); o[5] = f2bf(b.y); o[6] = f2bf(b.z); o[7] = f2bf(b.w);
  ((u16x8*)dst)[j] = o;
}

// ---------------------------------------------------------------------------
// OLD 128x128 gemm (m97 structure). Kept ONLY for PV (EPI=2): its grid at a
// 256-tile would be 128 blocks = half the CUs. Proven correct.
// ---------------------------------------------------------------------------
template <typename OT, int EPI>
__global__ __launch_bounds__(256) void gemm_bt(
    const u16* __restrict__ A, int lda, long zsA,
    const u16* __restrict__ B, int ldb, long zsB,
    OT* __restrict__ C, int ldc, long zsC,
    int K, float scale, const float* __restrict__ rs) {
  const int z = blockIdx.z;
  A += (long)z * zsA;
  B += (long)z * zsB;
  C += (long)z * zsC;
  if constexpr (EPI == 2) rs += (long)z * 4096;

  __shared__ __align__(16) u16 As[2 * 128 * 32];
  __shared__ __align__(16) u16 Bs[2 * 128 * 32];
  const int tid  = threadIdx.x;
  const int m0   = blockIdx.y * 128;
  const int n0   = blockIdx.x * 128;
  const int wave = tid >> 6;
  const int lane = tid & 63;
  const int wm   = (wave >> 1) * 64;
  const int wn   = (wave & 1) * 64;
  const int l15  = lane & 15;
  const int quad = lane >> 4;

  f32x4 acc[4][4];
#pragma unroll
  for (int i = 0; i < 4; ++i)
#pragma unroll
    for (int j = 0; j < 4; ++j) acc[i][j] = f32x4{0.f, 0.f, 0.f, 0.f};

  const u16* gA0 = A + (size_t)(m0 + (tid >> 2)) * lda + (tid & 3) * 8;
  const u16* gA1 = A + (size_t)(m0 + 64 + (tid >> 2)) * lda + (tid & 3) * 8;
  const u16* gB0 = B + (size_t)(n0 + (tid >> 2)) * ldb + (tid & 3) * 8;
  const u16* gB1 = B + (size_t)(n0 + 64 + (tid >> 2)) * ldb + (tid & 3) * 8;
  u16* lA0 = As + tid * 8;
  u16* lA1 = As + (256 + tid) * 8;
  u16* lB0 = Bs + tid * 8;
  u16* lB1 = Bs + (256 + tid) * 8;

  for (int k0 = 0; k0 < K; k0 += 64) {
    __syncthreads();
#pragma unroll
    for (int s = 0; s < 2; ++s) {
      gload_lds16(gA0 + k0 + s * 32, lA0 + s * 4096);
      gload_lds16(gA1 + k0 + s * 32, lA1 + s * 4096);
      gload_lds16(gB0 + k0 + s * 32, lB0 + s * 4096);
      gload_lds16(gB1 + k0 + s * 32, lB1 + s * 4096);
    }
    __syncthreads();

#pragma unroll
    for (int s = 0; s < 2; ++s) {
      u16x8 a[4], b[4];
#pragma unroll
      for (int i = 0; i < 4; ++i)
        a[i] = *(const u16x8*)(As + s * 4096 + (wm + i * 16 + l15) * 32 + quad * 8);
#pragma unroll
      for (int j = 0; j < 4; ++j)
        b[j] = *(const u16x8*)(Bs + s * 4096 + (wn + j * 16 + l15) * 32 + quad * 8);
#pragma unroll
      for (int i = 0; i < 4; ++i)
#pragma unroll
        for (int j = 0; j < 4; ++j)
          acc[i][j] = __builtin_amdgcn_mfma_f32_16x16x32_bf16(
              __builtin_bit_cast(bf16x8, a[i]), __builtin_bit_cast(bf16x8, b[j]),
              acc[i][j], 0, 0, 0);
    }
  }

#pragma unroll
  for (int i = 0; i < 4; ++i) {
#pragma unroll
    for (int r = 0; r < 4; ++r) {
      const int row = m0 + wm + i * 16 + quad * 4 + r;
      float mul = scale;
      if constexpr (EPI == 2) mul = scale / rs[row];
      const size_t ro = (size_t)row * ldc;
#pragma unroll
      for (int j = 0; j < 4; ++j) {
        float v = acc[i][j][r] * mul;
        if constexpr (EPI == 1) v = __expf(v);
        const int col = n0 + wn + j * 16 + l15;
        if constexpr (__is_same(OT, float))
          C[ro + col] = v;
        else
          C[ro + col] = f2bf(v);
      }
    }
  }
}

// ---------------------------------------------------------------------------
// NEW: 256x256-tile 8-phase pipelined GEMM (HK-style template, plain HIP).
// 512 thr = 8 waves (2M x 4N), per-wave C = 128x64 (acc[8][4]), BK=64.
// LDS: 2 K-tile buffers x (A 32KiB + B 32KiB) = 128 KiB. st_16x32 XOR swizzle
// (subtile 16 rows x 32 bf16 = 1024B; byte^=((byte>>9)&1)<<5) -> ds_read_b128
// residual conflict 4-way instead of 8-way. global_load_lds writes linearly;
// the swizzle is applied by pre-XORing the per-lane GLOBAL k (rule #21).
//
// Iteration = 2 K-tiles = 8 phases:
//   ph1: read buf0 A(qm0)+B(qn0) [12 ds_read_b128] | stage buf1.h2(t1) | MFMA Q00
//   ph2: read buf0 A(qm1)+B(qn1)                   | stage buf1.h3(t1) | MFMA Q01
//   ph3:                                            stage buf0.h0(t2) | MFMA Q10
//   ph4:                                            stage buf0.h1(t2) | vmcnt(4) | MFMA Q11
//   ph5-8: mirror on buf1, staging buf0.h2/h3(t2), buf1.h0/h1(t3), vmcnt(4) @ ph8
// Liveness proof: buf0 reads all issued ph1-2 (done at ph2 barrier) -> stages
// into buf0 at ph3-6 are WAR-safe; buf1 reads ph5-6 -> stages ph7..ph2 safe.
// vmcnt(4) at ph4 leaves exactly {t2.h0,t2.h1} outstanding => all of t1 landed
// before ph5 reads; at ph8 leaves {t3.h0,t3.h1} => all of t2 landed before the
// next iteration's ph1. Never drains to 0 except once on the last iteration.
// ---------------------------------------------------------------------------
#define BAR() __builtin_amdgcn_s_barrier()
#define PRIO(n) __builtin_amdgcn_s_setprio(n)
#define WAITV(n) asm volatile("s_waitcnt vmcnt(" #n ")" ::: "memory")

#define STG(c, h, q, t)                                                         \
  gload_lds16(((h) < 2 ? gAs : gBs) +                                           \
                  (size_t)(((h) & 1) * 128 + (q) * 64) * ((h) < 2 ? lda : ldb) + \
                  (size_t)(t) * 64,                                             \
              lds + (c) * 32768 + ((h) < 2 ? 0 : 16384) +                       \
                  (((h) & 1) * 8 + (q) * 4) * 1024 + wsub * 512)

#define LDA_Q(c, qm)                                                            \
  {                                                                             \
    _Pragma("unroll") for (int ii = 0; ii < 4; ++ii) {                          \
      _Pragma("unroll") for (int kk = 0; kk < 2; ++kk)                          \
          a[(qm) * 4 + ii][kk] = *(const u16x8*)(lds + (c) * 32768 +            \
              ((wm8 + (qm) * 4 + ii) * 2 + kk) * 512 + rq);                     \
    }                                                                           \
  }

#define LDB_Q(c, qn)                                                            \
  {                                                                             \
    _Pragma("unroll") for (int jj = 0; jj < 2; ++jj) {                          \
      _Pragma("unroll") for (int kk = 0; kk < 2; ++kk)                          \
          b[(qn) * 2 + jj][kk] = *(const u16x8*)(lds + (c) * 32768 + 16384 +    \
              ((wn4 + (qn) * 2 + jj) * 2 + kk) * 512 + rq);                     \
    }                                                                           \
  }

#define MFMA_Q(qm, qn)                                                          \
  {                                                                             \
    PRIO(1);                                                                    \
    _Pragma("unroll") for (int kk = 0; kk < 2; ++kk) {                          \
      _Pragma("unroll") for (int ii = 0; ii < 4; ++ii) {                        \
        _Pragma("unroll") for (int jj = 0; jj < 2; ++jj)                        \
            acc[(qm) * 4 + ii][(qn) * 2 + jj] =                                 \
                __builtin_amdgcn_mfma_f32_16x16x32_bf16(                        \
                    __builtin_bit_cast(bf16x8, a[(qm) * 4 + ii][kk]),           \
                    __builtin_bit_cast(bf16x8, b[(qn) * 2 + jj][kk]),           \
                    acc[(qm) * 4 + ii][(qn) * 2 + jj], 0, 0, 0);                \
      }                                                                         \
    }                                                                           \
    PRIO(0);                                                                    \
  }

template <typename OT, int EPI>
__global__ __launch_bounds__(512, 2) void gemm256(
    const u16* __restrict__ A, int lda, long zsA,
    const u16* __restrict__ B, int ldb, long zsB,
    OT* __restrict__ C, int ldc, long zsC,
    int K, float scale, const float* __restrict__ rs) {
  __shared__ __align__(16) u16 lds[65536];  // 128 KiB: [buf][A|B][16 rb][2 kb][512]
  const int z = blockIdx.z;
  A += (long)z * zsA;
  B += (long)z * zsB;
  C += (long)z * zsC;
  if constexpr (EPI == 2) rs += (long)z * 4096;

  const int tid  = threadIdx.x;
  const int lane = tid & 63;
  const int w    = tid >> 6;    // wave 0..7
  const int wm   = w >> 2;      // 0..1  (M)
  const int wn   = w & 3;       // 0..3  (N)
  const int wm8  = wm * 8;
  const int wn4  = wn * 4;
  const int l15  = lane & 15;
  const int quad = lane >> 4;
  const int m0   = blockIdx.y * 256;
  const int n0   = blockIdx.x * 256;

  // Staging: per call (2 per phase) the block writes 8 KiB = 8 subtiles; wave w
  // owns subtile (rowblock w>>1, kblock w&1); lane l -> row l>>2, k (l&3)*8,
  // with the k pre-XOR implementing the st_16x32 swizzle for rows >= 8.
  const int srow = (w >> 1) * 16 + (lane >> 2);
  const int kcol = ((lane & 3) * 8) ^ ((lane & 32) ? 16 : 0);
  const int skb  = w & 1;
  const u16* gAs = A + (size_t)(m0 + srow) * lda + skb * 32 + kcol;
  const u16* gBs = B + (size_t)(n0 + srow) * ldb + skb * 32 + kcol;
  const int wsub = (w >> 1) * 2 + skb;

  // Fragment read offset within a subtile (u16 units), swizzled.
  const int rq = (l15 * 32 + quad * 8) ^ ((l15 & 8) << 1);

  f32x4 acc[8][4];
#pragma unroll
  for (int i = 0; i < 8; ++i)
#pragma unroll
    for (int j = 0; j < 4; ++j) acc[i][j] = f32x4{0.f, 0.f, 0.f, 0.f};
  u16x8 a[8][2], b[4][2];

  const int ni = K >> 7;  // iterations of 2 K-tiles (K % 128 == 0)

  // Prologue: tile0 -> buf0 fully; tile1 -> buf1 halves h0,h1. 12 loads; keep
  // the 4 t1 loads in flight (vmcnt(4)), t0 landed before ph1 reads.
#pragma unroll
  for (int h = 0; h < 4; ++h) { STG(0, h, 0, 0); STG(0, h, 1, 0); }
  STG(1, 0, 0, 1); STG(1, 0, 1, 1);
  STG(1, 1, 0, 1); STG(1, 1, 1, 1);
  WAITV(4);
  BAR();

  for (int i = 0; i < ni; ++i) {
    const int t1 = 2 * i + 1, t2 = 2 * i + 2, t3 = 2 * i + 3;
    const bool more = (i + 1 < ni);

    // ph1
    LDA_Q(0, 0); LDB_Q(0, 0);
    STG(1, 2, 0, t1); STG(1, 2, 1, t1);
    BAR(); MFMA_Q(0, 0); BAR();
    // ph2
    LDA_Q(0, 1); LDB_Q(0, 1);
    STG(1, 3, 0, t1); STG(1, 3, 1, t1);
    BAR(); MFMA_Q(0, 1); BAR();
    // ph3
    if (more) { STG(0, 0, 0, t2); STG(0, 0, 1, t2); }
    BAR(); MFMA_Q(1, 0); BAR();
    // ph4
    if (more) { STG(0, 1, 0, t2); STG(0, 1, 1, t2); WAITV(4); }
    else { WAITV(0); }
    BAR(); MFMA_Q(1, 1); BAR();
    // ph5
    LDA_Q(1, 0); LDB_Q(1, 0);
    if (more) { STG(0, 2, 0, t2); STG(0, 2, 1, t2); }
    BAR(); MFMA_Q(0, 0); BAR();
    // ph6
    LDA_Q(1, 1); LDB_Q(1, 1);
    if (more) { STG(0, 3, 0, t2); STG(0, 3, 1, t2); }
    BAR(); MFMA_Q(0, 1); BAR();
    // ph7
    if (more) { STG(1, 0, 0, t3); STG(1, 0, 1, t3); }
    BAR(); MFMA_Q(1, 0); BAR();
    // ph8
    if (more) { STG(1, 1, 0, t3); STG(1, 1, 1, t3); WAITV(4); }
    BAR(); MFMA_Q(1, 1); BAR();
  }

  // Epilogue. C/D layout (m89-verified): col = lane&15, row = (lane>>4)*4 + reg
#pragma unroll
  for (int i = 0; i < 8; ++i) {
#pragma unroll
    for (int r = 0; r < 4; ++r) {
      const int row = m0 + wm * 128 + i * 16 + quad * 4 + r;
      float mul = scale;
      if constexpr (EPI == 2) mul = scale / rs[row];
      const size_t ro = (size_t)row * ldc;
#pragma unroll
      for (int j = 0; j < 4; ++j) {
        float v = acc[i][j][r] * mul;
        if constexpr (EPI == 1) v = __expf(v);
        const int col = n0 + wn * 64 + j * 16 + l15;
        if constexpr (__is_same(OT, float))
          C[ro + col] = v;
        else
          C[ro + col] = f2bf(v);
      }
    }
  }
}

// rs[z*4096+row] = sum over 4096 cols of P[z][row][*] (bf16). Direct write.
__global__ __launch_bounds__(256) void rowsum_rows(
    const u16* __restrict__ P, long zsP, float* __restrict__ rs) {
  const int row = blockIdx.x;
  const int z   = blockIdx.y;
  const u16* p = P + (long)z * zsP + (size_t)row * 4096;
  const int tid  = threadIdx.x;
  const int lane = tid & 63;
  const int wave = tid >> 6;

  u16x8 h0 = *(const u16x8*)(p + tid * 16);
  u16x8 h1 = *(const u16x8*)(p + tid * 16 + 8);
  float s = 0.f;
#pragma unroll
  for (int j = 0; j < 8; ++j) s += bf2f(h0[j]) + bf2f(h1[j]);
  for (int o = 32; o > 0; o >>= 1) s += __shfl_xor(s, o, 64);
  __shared__ float red[4];
  if (lane == 0) red[wave] = s;
  __syncthreads();
  if (tid == 0) rs[(size_t)z * 4096 + row] = red[0] + red[1] + red[2] + red[3];
}

// Vt[z][d, s] = V[z][s, d].
__global__ __launch_bounds__(256) void transpose_v(
    const u16* __restrict__ V, int ldv, long zsV,
    u16* __restrict__ Vt, int ldt, long zsT) {
  const int z = blockIdx.z;
  V  += (long)z * zsV;
  Vt += (long)z * zsT;
  __shared__ u16 T[64][65];
  const int d0 = blockIdx.x * 64;
  const int s0 = blockIdx.y * 64;
  const int tid = threadIdx.x;
  const int c = tid & 63;
  const int rbase = (tid >> 6) * 16;
#pragma unroll
  for (int r = 0; r < 16; ++r)
    T[rbase + r][c] = V[(size_t)(s0 + rbase + r) * ldv + d0 + c];
  __syncthreads();
#pragma unroll
  for (int r = 0; r < 16; ++r)
    Vt[(size_t)(d0 + rbase + r) * ldt + s0 + c] = T[c][rbase + r];
}

extern "C" void kernel_launch(void* const* d_in, const int* in_sizes, int n_in,
                              void* d_out, int out_size, void* d_ws, size_t ws_size,
                              hipStream_t stream) {
  const float* x    = (const float*)d_in[0];  // [B*S, D] fp32
  const float* Wqkv = (const float*)d_in[1];  // [3D, D]  fp32
  const float* Wo   = (const float*)d_in[2];  // [D, D]   fp32
  float* out = (float*)d_out;                 // [B*S, D] fp32

  const int Bn = 4, S = 4096, D = 1024;
  const int M = Bn * S;  // 16384
  const int E = 3 * D;   // 3072
  const long SE = (long)S * E, SS = (long)S * S, DS = (long)D * S, SD = (long)S * D;

  const int nz = (ws_size >= (size_t)226492416) ? 2 : 1;  // 216 MB

  char* ws = (char*)d_ws;
  size_t off = 0;
  u16* qkv = (u16*)(ws + off);  off += (size_t)M * E * 2;        // 96 MB
  u16* Sb  = (u16*)(ws + off);  off += (size_t)nz * S * S * 2;   // nz*32 MB
  u16* Vt  = (u16*)(ws + off);  off += (size_t)nz * D * S * 2;   // nz*8 MB
  u16* xb  = (u16*)(ws + off);  off += (size_t)M * D * 2;        // 32 MB
  u16* attn = xb;                 // xb dead after QKV proj
  u16* Wqkvb = (u16*)(ws + off); off += (size_t)E * D * 2;       // 6 MB
  u16* Wob   = (u16*)(ws + off); off += (size_t)D * D * 2;       // 2 MB
  float* rs = (float*)Wqkvb;      // aliases Wqkvb (dead after QKV gemm)

  // 0) fp32 -> bf16 converts (fused)
  const int n1 = M * D / 8, n2 = E * D / 8, n3 = D * D / 8;
  cvt_all<<<(n1 + n2 + n3 + 255) / 256, 256, 0, stream>>>(
      x, Wqkv, Wo, xb, Wqkvb, Wob, n1, n2, n3);

  // 1) QKV projection: qkv = xb @ Wqkvb^T   [16384 x 3072], 12x64 = 768 blocks
  gemm256<u16, 0><<<dim3(E / 256, M / 256, 1), 512, 0, stream>>>(
      xb, D, 0, Wqkvb, D, 0, qkv, E, 0, D, 1.0f, nullptr);

  const float scl = 0.03125f;  // 1/sqrt(1024)
  for (int c = 0; c < Bn; c += nz) {
    const u16* Qc = qkv + (size_t)c * SE;
    transpose_v<<<dim3(D / 64, S / 64, nz), 256, 0, stream>>>(
        Qc + 2 * D, E, SE, Vt, S, DS);
    // QK^T with exp epilogue: 16x16xnz blocks (512 @ nz=2)
    gemm256<u16, 1><<<dim3(S / 256, S / 256, nz), 512, 0, stream>>>(
        Qc, E, SE, Qc + D, E, SE, Sb, S, SS, D, scl, nullptr);
    rowsum_rows<<<dim3(S, nz), 256, 0, stream>>>(Sb, SS, rs);
    // PV stays on 128^2 kernel: 256-tile grid would be only 128 blocks.
    gemm_bt<u16, 2><<<dim3(D / 128, S / 128, nz), 256, 0, stream>>>(
        Sb, S, SS, Vt, S, DS, attn + (size_t)c * SD, D, SD, S, 1.0f, rs);
  }

  // 2) out = attn @ Wo^T  [16384 x 1024] -> fp32, 4x64 = 256 blocks
  gemm256<float, 0><<<dim3(D / 256, M / 256, 1), 512, 0, stream>>>(
      attn, D, 0, Wob, D, 0, out, D, 0, D, 1.0f, nullptr);
}